// Round 1
// baseline (2217.578 us; speedup 1.0000x reference)
//
#include <hip/hip_runtime.h>

typedef _Float16 f16;
typedef _Float16 f16x8 __attribute__((ext_vector_type(8)));
typedef float f32x4 __attribute__((ext_vector_type(4)));

#define NB   8
#define HW   5476
#define NL   32
#define DIM  1024
#define LIN  768
#define MTOT (NB * HW)            // 43808
#define MTILES ((MTOT + 127) / 128) // 343

// ---------------------------------------------------------------- utilities

__device__ __forceinline__ void g2l16(const void* g, void* l) {
#if __has_builtin(__builtin_amdgcn_global_load_lds)
  __builtin_amdgcn_global_load_lds(
      (const __attribute__((address_space(1))) void*)g,
      (__attribute__((address_space(3))) void*)l, 16, 0, 0);
#else
  const int lane = threadIdx.x & 63;
  *(uint4*)((char*)l + lane * 16) = *(const uint4*)g;
#endif
}

__device__ __forceinline__ float gelu_f(float x) {
  return 0.5f * x * (1.0f + erff(x * 0.70710678118654752f));
}

// ---------------------------------------------------------------- big GEMM
// C[M,N] = A[M,K] * W[N,K]^T (+bias, epilogue). K = N = 1024.
// EPI: 0 = gelu->f16, 1 = plain->f16, 2 = plain->f32, 3 = gelu->f32
template <int EPI>
__global__ __launch_bounds__(256) void gemm_nt(
    const f16* __restrict__ A, const f16* __restrict__ W,
    const float* __restrict__ bias, void* __restrict__ out, int M) {
  constexpr int K = 1024, N = 1024;
  __shared__ f16 As[128 * 64];  // [m][k], row stride 64 elements (128B)
  __shared__ f16 Bs[128 * 64];  // [n][k]

  const int tid = threadIdx.x;
  const int wave = tid >> 6, lane = tid & 63;
  const int m0 = blockIdx.y * 128, n0 = blockIdx.x * 128;
  const int wm = (wave >> 1) * 64, wn = (wave & 1) * 64;
  const int fr = lane & 15, fq = lane >> 4;

  f32x4 acc[4][4];
#pragma unroll
  for (int i = 0; i < 4; ++i)
#pragma unroll
    for (int j = 0; j < 4; ++j) acc[i][j] = (f32x4){0.f, 0.f, 0.f, 0.f};

  const int sub = lane >> 3;        // 0..7 rows within an 8-row chunk
  const int scol = (lane & 7) * 8;  // element offset in k (16B per lane)

  for (int it = 0; it < K / 64; ++it) {
    const int k0 = it * 64;
#pragma unroll
    for (int i = 0; i < 4; ++i) {
      const int r = wave * 32 + i * 8;
      int gm = m0 + r + sub;
      if (gm > M - 1) gm = M - 1;
      g2l16(A + (size_t)gm * K + k0 + scol, &As[r * 64]);
    }
#pragma unroll
    for (int i = 0; i < 4; ++i) {
      const int r = wave * 32 + i * 8;
      g2l16(W + (size_t)(n0 + r + sub) * K + k0 + scol, &Bs[r * 64]);
    }
    __syncthreads();
#pragma unroll
    for (int kk = 0; kk < 2; ++kk) {
      const int ko = kk * 32 + fq * 8;
      f16x8 af[4], bf[4];
#pragma unroll
      for (int i = 0; i < 4; ++i)
        af[i] = *(const f16x8*)&As[(wm + i * 16 + fr) * 64 + ko];
#pragma unroll
      for (int j = 0; j < 4; ++j)
        bf[j] = *(const f16x8*)&Bs[(wn + j * 16 + fr) * 64 + ko];
#pragma unroll
      for (int i = 0; i < 4; ++i)
#pragma unroll
        for (int j = 0; j < 4; ++j)
          acc[i][j] = __builtin_amdgcn_mfma_f32_16x16x32_f16(af[i], bf[j],
                                                             acc[i][j], 0, 0, 0);
    }
    __syncthreads();
  }

  // Epilogue. C/D layout: col = lane&15, row = (lane>>4)*4 + reg (HW-verified).
  const int row0 = m0 + wm + fq * 4;
  const int col0 = n0 + wn + fr;
#pragma unroll
  for (int j = 0; j < 4; ++j) {
    const int col = col0 + j * 16;
    const float bv = bias[col];
#pragma unroll
    for (int i = 0; i < 4; ++i) {
#pragma unroll
      for (int r = 0; r < 4; ++r) {
        const int row = row0 + i * 16 + r;
        if (row < M) {
          float v = acc[i][j][r] + bv;
          if constexpr (EPI == 0 || EPI == 3) v = gelu_f(v);
          if constexpr (EPI <= 1)
            ((f16*)out)[(size_t)row * N + col] = (f16)v;
          else
            ((float*)out)[(size_t)row * N + col] = v;
        }
      }
    }
  }
}

// ---------------------------------------------------------------- fp32 -> fp16
__global__ void cvt_f32_f16(const float* __restrict__ in, f16* __restrict__ out,
                            int nchunks) {
  const int i = blockIdx.x * 256 + threadIdx.x;
  if (i >= nchunks) return;
  const float4* p = (const float4*)in + (size_t)i * 2;
  const float4 a = p[0], b = p[1];
  f16x8 o = {(f16)a.x, (f16)a.y, (f16)a.z, (f16)a.w,
             (f16)b.x, (f16)b.y, (f16)b.z, (f16)b.w};
  *((f16x8*)out + i) = o;
}

// ---------------------------------------------------------------- column stats
// Per (b, channel) mean / rsqrt(var+eps) over length HW. X is [NB*HW, DIM].
template <typename T>
__global__ __launch_bounds__(256) void colstats(const T* __restrict__ X,
                                                float* __restrict__ mean,
                                                float* __restrict__ rinv) {
  const int b = blockIdx.y;
  const int c0 = blockIdx.x * 32;
  const int col = threadIdx.x & 31, rg = threadIdx.x >> 5;  // 32 cols x 8 rows
  const T* base = X + (size_t)b * HW * DIM + c0 + col;
  float s = 0.f, sq = 0.f;
  for (int l = rg; l < HW; l += 8) {
    const float v = (float)base[(size_t)l * DIM];
    s += v;
    sq += v * v;
  }
  __shared__ float ss[8][32], qq[8][32];
  ss[rg][col] = s;
  qq[rg][col] = sq;
  __syncthreads();
  if (threadIdx.x < 32) {
    s = 0.f;
    sq = 0.f;
#pragma unroll
    for (int r = 0; r < 8; ++r) {
      s += ss[r][col];
      sq += qq[r][col];
    }
    const float m = s * (1.0f / HW);
    const float var = sq * (1.0f / HW) - m * m;
    mean[b * DIM + c0 + col] = m;
    rinv[b * DIM + c0 + col] = rsqrtf(var + 1e-5f);
  }
}

// ---------------------------------------------------------------- k/v small GEMM
// out[b][o][n] = (sum_c w[o,c]*l[b,n,c] + bias[o]) * mask[b,n]
__global__ __launch_bounds__(256) void kv_gemm(
    const float* __restrict__ l, const float* __restrict__ lmask,
    const float* __restrict__ wk, const float* __restrict__ bk,
    const float* __restrict__ wv, const float* __restrict__ bv,
    float* __restrict__ Kout, float* __restrict__ Vout) {
  const int b = blockIdx.z;
  const int o0 = blockIdx.x * 64;
  const float* w = blockIdx.y ? wv : wk;
  const float* bb = blockIdx.y ? bv : bk;
  float* out = blockIdx.y ? Vout : Kout;

  __shared__ float wl[64 * 129];
  __shared__ float ll[32 * 129];
  const int tid = threadIdx.x;
  const int o = tid & 63, ng = tid >> 6;  // each thread: 1 o x 8 n
  float acc[8];
#pragma unroll
  for (int j = 0; j < 8; ++j) acc[j] = 0.f;

  for (int kc = 0; kc < LIN; kc += 128) {
    for (int e = tid; e < 64 * 128; e += 256)
      wl[(e >> 7) * 129 + (e & 127)] =
          w[(size_t)(o0 + (e >> 7)) * LIN + kc + (e & 127)];
    for (int e = tid; e < 32 * 128; e += 256)
      ll[(e >> 7) * 129 + (e & 127)] =
          l[(size_t)b * NL * LIN + (size_t)(e >> 7) * LIN + kc + (e & 127)];
    __syncthreads();
    for (int k = 0; k < 128; ++k) {
      const float wv_ = wl[o * 129 + k];
#pragma unroll
      for (int j = 0; j < 8; ++j) acc[j] += wv_ * ll[(ng * 8 + j) * 129 + k];
    }
    __syncthreads();
  }
  const float bval = bb[o0 + o];
#pragma unroll
  for (int j = 0; j < 8; ++j) {
    const int n = ng * 8 + j;
    out[((size_t)b * DIM + o0 + o) * NL + n] =
        (acc[j] + bval) * lmask[b * NL + n];
  }
}

// ---------------------------------------------------------------- attention
// Per (b,h,m): scores over 32 keys (dk=128), softmax, weighted sum of v (dv=128).
__global__ __launch_bounds__(256) void attn_kernel(
    const f16* __restrict__ Q, const float* __restrict__ qmean,
    const float* __restrict__ qrinv, const float* __restrict__ Kk,
    const float* __restrict__ Vv, const float* __restrict__ lmask,
    float* __restrict__ Out) {
  const int b = blockIdx.z, h = blockIdx.y;
  __shared__ float ks[128 * NL], vs[128 * NL], qm[128], qr[128], bs[NL];
  const int tid = threadIdx.x;
  const float* kbase = Kk + ((size_t)b * DIM + h * 128) * NL;
  const float* vbase = Vv + ((size_t)b * DIM + h * 128) * NL;
  for (int i = tid; i < 128 * NL; i += 256) {
    ks[i] = kbase[i];
    vs[i] = vbase[i];
  }
  if (tid < 128) {
    qm[tid] = qmean[b * DIM + h * 128 + tid];
    qr[tid] = qrinv[b * DIM + h * 128 + tid];
  }
  if (tid < NL) bs[tid] = (lmask[b * NL + tid] - 1.0f) * 10000.0f;
  __syncthreads();

  const int mloc = blockIdx.x * 256 + tid;
  if (mloc >= HW) return;
  const size_t m = (size_t)b * HW + mloc;
  const f16* qrow = Q + m * DIM + h * 128;

  float sc[32];
#pragma unroll
  for (int n = 0; n < 32; ++n) sc[n] = 0.f;

  for (int d8 = 0; d8 < 16; ++d8) {
    const f16x8 qv = *(const f16x8*)(qrow + d8 * 8);
#pragma unroll
    for (int j = 0; j < 8; ++j) {
      const int d = d8 * 8 + j;
      const float qd = ((float)qv[j] - qm[d]) * qr[d];
      const float4* kr = (const float4*)&ks[d * 32];
#pragma unroll
      for (int n4 = 0; n4 < 8; ++n4) {
        const float4 kk = kr[n4];
        sc[n4 * 4 + 0] += qd * kk.x;
        sc[n4 * 4 + 1] += qd * kk.y;
        sc[n4 * 4 + 2] += qd * kk.z;
        sc[n4 * 4 + 3] += qd * kk.w;
      }
    }
  }
  float mx = -1e30f;
#pragma unroll
  for (int n = 0; n < 32; ++n) {
    sc[n] = sc[n] * 0.03125f + bs[n];  // * KC^-0.5 then masked bias
    mx = fmaxf(mx, sc[n]);
  }
  float sum = 0.f;
#pragma unroll
  for (int n = 0; n < 32; ++n) {
    sc[n] = __expf(sc[n] - mx);
    sum += sc[n];
  }
  const float rs = 1.0f / sum;

  float* orow = Out + m * DIM + h * 128;
  for (int dv8 = 0; dv8 < 16; ++dv8) {
    float ov[8];
#pragma unroll
    for (int j = 0; j < 8; ++j) {
      const float4* vr = (const float4*)&vs[(dv8 * 8 + j) * 32];
      float a = 0.f;
#pragma unroll
      for (int n4 = 0; n4 < 8; ++n4) {
        const float4 vv = vr[n4];
        a += sc[n4 * 4 + 0] * vv.x + sc[n4 * 4 + 1] * vv.y +
             sc[n4 * 4 + 2] * vv.z + sc[n4 * 4 + 3] * vv.w;
      }
      ov[j] = a * rs;
    }
    float4* op = (float4*)(orow + dv8 * 8);
    op[0] = make_float4(ov[0], ov[1], ov[2], ov[3]);
    op[1] = make_float4(ov[4], ov[5], ov[6], ov[7]);
  }
}

// ---------------------------------------------------------------- center (attn - colmean) -> f16
__global__ void center_kernel(const float* __restrict__ X,
                              const float* __restrict__ mean,
                              f16* __restrict__ out, int nchunks) {
  const int i = blockIdx.x * 256 + threadIdx.x;
  if (i >= nchunks) return;
  const size_t e = (size_t)i * 8;
  const int mrow = (int)(e >> 10);
  const int o = (int)(e & 1023);
  const int b = mrow / HW;
  const float4* p = (const float4*)(X + e);
  const float4 a = p[0], c = p[1];
  const float* mn = mean + b * DIM + o;
  f16x8 r = {(f16)(a.x - mn[0]), (f16)(a.y - mn[1]), (f16)(a.z - mn[2]),
             (f16)(a.w - mn[3]), (f16)(c.x - mn[4]), (f16)(c.y - mn[5]),
             (f16)(c.z - mn[6]), (f16)(c.w - mn[7])};
  *((f16x8*)out + i) = r;
}

// ---------------------------------------------------------------- fuse: mm = vis * inorm(lang_pre)
__global__ void fuse_kernel(const f16* __restrict__ vis,
                            const float* __restrict__ lang,
                            const float* __restrict__ mean,
                            const float* __restrict__ rinv,
                            f16* __restrict__ out, int nchunks) {
  const int i = blockIdx.x * 256 + threadIdx.x;
  if (i >= nchunks) return;
  const size_t e = (size_t)i * 8;
  const int mrow = (int)(e >> 10);
  const int o = (int)(e & 1023);
  const int b = mrow / HW;
  const f16x8 v = *((const f16x8*)vis + i);
  const float4* p = (const float4*)(lang + e);
  const float4 a = p[0], c = p[1];
  const float lv[8] = {a.x, a.y, a.z, a.w, c.x, c.y, c.z, c.w};
  const float* mn = mean + b * DIM + o;
  const float* ri = rinv + b * DIM + o;
  f16x8 r;
#pragma unroll
  for (int j = 0; j < 8; ++j)
    r[j] = (f16)((float)v[j] * ((lv[j] - mn[j]) * ri[j]));
  *((f16x8*)out + i) = r;
}

// ---------------------------------------------------------------- launch
extern "C" void kernel_launch(void* const* d_in, const int* in_sizes, int n_in,
                              void* d_out, int out_size, void* d_ws,
                              size_t ws_size, hipStream_t stream) {
  const float* x     = (const float*)d_in[0];
  const float* l     = (const float*)d_in[1];
  const float* lmask = (const float*)d_in[2];
  const float* vis_w = (const float*)d_in[3];
  const float* vis_b = (const float*)d_in[4];
  const float* fq_w  = (const float*)d_in[5];
  const float* fq_b  = (const float*)d_in[6];
  const float* fk_w  = (const float*)d_in[7];
  const float* fk_b  = (const float*)d_in[8];
  const float* fv_w  = (const float*)d_in[9];
  const float* fv_b  = (const float*)d_in[10];
  const float* W_w   = (const float*)d_in[11];
  const float* W_b   = (const float*)d_in[12];
  const float* pm_w  = (const float*)d_in[13];
  const float* pm_b  = (const float*)d_in[14];

  char* ws = (char*)d_ws;
  const size_t SB = (size_t)MTOT * DIM * 2;  // one f16 [M,1024] buffer
  f16* Ah = (f16*)(ws);                      // x_f16 -> centered attn -> mm
  f16* Bh = (f16*)(ws + SB);                 // vis
  f16* Ch = (f16*)(ws + 2 * SB);             // q (f16)
  float* Df = (float*)(ws + 3 * SB);         // attn f32 -> lang_pre f32 (2*SB bytes)
  char* wsp = ws + 5 * SB;
  f16* vis_wh = (f16*)(wsp);
  f16* fq_wh  = (f16*)(wsp + (1 << 21));
  f16* W_wh   = (f16*)(wsp + 2 * (1 << 21));
  f16* pm_wh  = (f16*)(wsp + 3 * (1 << 21));
  float* Kout = (float*)(wsp + 4 * (1 << 21));
  float* Vout = (float*)(wsp + 4 * (1 << 21) + (1 << 20));
  float* st   = (float*)(wsp + 4 * (1 << 21) + 2 * (1 << 20));
  float* qmean = st;
  float* qrinv = st + 8192;
  float* amean = st + 16384;
  float* arinv = st + 24576;
  float* lmean = st + 32768;
  float* lrinv = st + 40960;

  const int NCH_BIG = MTOT * DIM / 8;  // 5,607,424 chunks of 8
  const int NCH_W = DIM * DIM / 8;     // 131,072

  cvt_f32_f16<<<(NCH_BIG + 255) / 256, 256, 0, stream>>>(x, Ah, NCH_BIG);
  cvt_f32_f16<<<(NCH_W + 255) / 256, 256, 0, stream>>>(vis_w, vis_wh, NCH_W);
  cvt_f32_f16<<<(NCH_W + 255) / 256, 256, 0, stream>>>(fq_w, fq_wh, NCH_W);
  cvt_f32_f16<<<(NCH_W + 255) / 256, 256, 0, stream>>>(W_w, W_wh, NCH_W);
  cvt_f32_f16<<<(NCH_W + 255) / 256, 256, 0, stream>>>(pm_w, pm_wh, NCH_W);

  kv_gemm<<<dim3(16, 2, 8), 256, 0, stream>>>(l, lmask, fk_w, fk_b, fv_w, fv_b,
                                              Kout, Vout);

  const dim3 ggrid(8, MTILES);
  gemm_nt<0><<<ggrid, 256, 0, stream>>>(Ah, vis_wh, vis_b, Bh, MTOT);  // vis
  gemm_nt<1><<<ggrid, 256, 0, stream>>>(Ah, fq_wh, fq_b, Ch, MTOT);    // q_pre

  colstats<f16><<<dim3(32, 8), 256, 0, stream>>>(Ch, qmean, qrinv);

  attn_kernel<<<dim3((HW + 255) / 256, 8, 8), 256, 0, stream>>>(
      Ch, qmean, qrinv, Kout, Vout, lmask, Df);

  colstats<float><<<dim3(32, 8), 256, 0, stream>>>(Df, amean, arinv);
  center_kernel<<<(NCH_BIG + 255) / 256, 256, 0, stream>>>(Df, amean, Ah,
                                                           NCH_BIG);

  gemm_nt<2><<<ggrid, 256, 0, stream>>>(Ah, W_wh, W_b, Df, MTOT);  // lang_pre f32
  colstats<float><<<dim3(32, 8), 256, 0, stream>>>(Df, lmean, lrinv);
  fuse_kernel<<<(NCH_BIG + 255) / 256, 256, 0, stream>>>(Bh, Df, lmean, lrinv,
                                                         Ah, NCH_BIG);

  gemm_nt<3><<<ggrid, 256, 0, stream>>>(Ah, pm_wh, pm_b, d_out, MTOT);  // output
}

// Round 2
// 1648.341 us; speedup vs baseline: 1.3453x; 1.3453x over previous
//
#include <hip/hip_runtime.h>

typedef _Float16 f16;
typedef _Float16 f16x4 __attribute__((ext_vector_type(4)));
typedef _Float16 f16x8 __attribute__((ext_vector_type(8)));
typedef float f32x4 __attribute__((ext_vector_type(4)));

#define NB   8
#define HW   5476
#define NL   32
#define DIM  1024
#define LIN  768
#define MTOT (NB * HW)            // 43808
#define MTILES ((MTOT + 127) / 128) // 343
#define CSPLIT 128                // colstats row-splits per batch

// ---------------------------------------------------------------- utilities

__device__ __forceinline__ void g2l16(const void* g, void* l) {
#if __has_builtin(__builtin_amdgcn_global_load_lds)
  __builtin_amdgcn_global_load_lds(
      (const __attribute__((address_space(1))) void*)g,
      (__attribute__((address_space(3))) void*)l, 16, 0, 0);
#else
  const int lane = threadIdx.x & 63;
  *(uint4*)((char*)l + lane * 16) = *(const uint4*)g;
#endif
}

__device__ __forceinline__ float gelu_f(float x) {
  return 0.5f * x * (1.0f + erff(x * 0.70710678118654752f));
}

// ---------------------------------------------------------------- big GEMM
// C[M,N] = A[M,K] * W[N,K]^T (+bias, epilogue). K = N = 1024.
// EPI: 0 = gelu->f16, 1 = plain->f16, 2 = plain->f32, 3 = gelu->f32
template <int EPI>
__global__ __launch_bounds__(256) void gemm_nt(
    const f16* __restrict__ A, const f16* __restrict__ W,
    const float* __restrict__ bias, void* __restrict__ out, int M) {
  constexpr int K = 1024, N = 1024;
  __shared__ f16 As[128 * 64];  // [m][k], row stride 64 elements (128B)
  __shared__ f16 Bs[128 * 64];  // [n][k]

  const int tid = threadIdx.x;
  const int wave = tid >> 6, lane = tid & 63;
  const int m0 = blockIdx.y * 128, n0 = blockIdx.x * 128;
  const int wm = (wave >> 1) * 64, wn = (wave & 1) * 64;
  const int fr = lane & 15, fq = lane >> 4;

  f32x4 acc[4][4];
#pragma unroll
  for (int i = 0; i < 4; ++i)
#pragma unroll
    for (int j = 0; j < 4; ++j) acc[i][j] = (f32x4){0.f, 0.f, 0.f, 0.f};

  const int sub = lane >> 3;        // 0..7 rows within an 8-row chunk
  const int scol = (lane & 7) * 8;  // element offset in k (16B per lane)

  for (int it = 0; it < K / 64; ++it) {
    const int k0 = it * 64;
#pragma unroll
    for (int i = 0; i < 4; ++i) {
      const int r = wave * 32 + i * 8;
      int gm = m0 + r + sub;
      if (gm > M - 1) gm = M - 1;
      g2l16(A + (size_t)gm * K + k0 + scol, &As[r * 64]);
    }
#pragma unroll
    for (int i = 0; i < 4; ++i) {
      const int r = wave * 32 + i * 8;
      g2l16(W + (size_t)(n0 + r + sub) * K + k0 + scol, &Bs[r * 64]);
    }
    __syncthreads();
#pragma unroll
    for (int kk = 0; kk < 2; ++kk) {
      const int ko = kk * 32 + fq * 8;
      f16x8 af[4], bf[4];
#pragma unroll
      for (int i = 0; i < 4; ++i)
        af[i] = *(const f16x8*)&As[(wm + i * 16 + fr) * 64 + ko];
#pragma unroll
      for (int j = 0; j < 4; ++j)
        bf[j] = *(const f16x8*)&Bs[(wn + j * 16 + fr) * 64 + ko];
#pragma unroll
      for (int i = 0; i < 4; ++i)
#pragma unroll
        for (int j = 0; j < 4; ++j)
          acc[i][j] = __builtin_amdgcn_mfma_f32_16x16x32_f16(af[i], bf[j],
                                                             acc[i][j], 0, 0, 0);
    }
    __syncthreads();
  }

  // Epilogue. C/D layout: col = lane&15, row = (lane>>4)*4 + reg (HW-verified).
  const int row0 = m0 + wm + fq * 4;
  const int col0 = n0 + wn + fr;
#pragma unroll
  for (int j = 0; j < 4; ++j) {
    const int col = col0 + j * 16;
    const float bv = bias[col];
#pragma unroll
    for (int i = 0; i < 4; ++i) {
#pragma unroll
      for (int r = 0; r < 4; ++r) {
        const int row = row0 + i * 16 + r;
        if (row < M) {
          float v = acc[i][j][r] + bv;
          if constexpr (EPI == 0 || EPI == 3) v = gelu_f(v);
          if constexpr (EPI <= 1)
            ((f16*)out)[(size_t)row * N + col] = (f16)v;
          else
            ((float*)out)[(size_t)row * N + col] = v;
        }
      }
    }
  }
}

// ---------------------------------------------------------------- fp32 -> fp16
__global__ void cvt_f32_f16(const float* __restrict__ in, f16* __restrict__ out,
                            int nchunks) {
  const int i = blockIdx.x * 256 + threadIdx.x;
  if (i >= nchunks) return;
  const float4* p = (const float4*)in + (size_t)i * 2;
  const float4 a = p[0], b = p[1];
  f16x8 o = {(f16)a.x, (f16)a.y, (f16)a.z, (f16)a.w,
             (f16)b.x, (f16)b.y, (f16)b.z, (f16)b.w};
  *((f16x8*)out + i) = o;
}

// ---------------------------------------------------------------- column stats
// Two-stage: stage A (coalesced partial sums over row splits), stage B (reduce).
// X is [NB*HW, DIM] row-major. Partials are [CSPLIT, NB, DIM].
template <typename T>
__global__ __launch_bounds__(256) void colstats_partial(
    const T* __restrict__ X, float* __restrict__ psum,
    float* __restrict__ psq) {
  const int b = blockIdx.y;
  const int sp = blockIdx.x;
  const int c = threadIdx.x * 4;  // 4 columns per thread
  constexpr int CHUNK = (HW + CSPLIT - 1) / CSPLIT;  // 43
  const int r0 = sp * CHUNK;
  const int r1 = (r0 + CHUNK < HW) ? r0 + CHUNK : HW;

  float s0 = 0.f, s1 = 0.f, s2 = 0.f, s3 = 0.f;
  float q0 = 0.f, q1 = 0.f, q2 = 0.f, q3 = 0.f;
  const T* base = X + ((size_t)b * HW + r0) * DIM + c;
  for (int r = r0; r < r1; ++r) {
    float v0, v1, v2, v3;
    if constexpr (sizeof(T) == 2) {
      const f16x4 v = *(const f16x4*)base;
      v0 = (float)v[0]; v1 = (float)v[1]; v2 = (float)v[2]; v3 = (float)v[3];
    } else {
      const float4 v = *(const float4*)base;
      v0 = v.x; v1 = v.y; v2 = v.z; v3 = v.w;
    }
    s0 += v0; s1 += v1; s2 += v2; s3 += v3;
    q0 += v0 * v0; q1 += v1 * v1; q2 += v2 * v2; q3 += v3 * v3;
    base += DIM;
  }
  const size_t o = ((size_t)sp * NB + b) * DIM + c;
  *(float4*)&psum[o] = make_float4(s0, s1, s2, s3);
  *(float4*)&psq[o] = make_float4(q0, q1, q2, q3);
}

__global__ __launch_bounds__(256) void colstats_final(
    const float* __restrict__ psum, const float* __restrict__ psq,
    float* __restrict__ mean, float* __restrict__ rinv) {
  const int i = blockIdx.x * 256 + threadIdx.x;  // over NB*DIM = 8192
  float s = 0.f, q = 0.f;
  for (int sp = 0; sp < CSPLIT; ++sp) {
    s += psum[(size_t)sp * NB * DIM + i];
    q += psq[(size_t)sp * NB * DIM + i];
  }
  const float m = s * (1.0f / HW);
  const float var = q * (1.0f / HW) - m * m;
  mean[i] = m;
  rinv[i] = rsqrtf(var + 1e-5f);
}

// ---------------------------------------------------------------- k/v small GEMM
// out[b][o][n] = (sum_c w[o,c]*l[b,n,c] + bias[o]) * mask[b,n]
__global__ __launch_bounds__(256) void kv_gemm(
    const float* __restrict__ l, const float* __restrict__ lmask,
    const float* __restrict__ wk, const float* __restrict__ bk,
    const float* __restrict__ wv, const float* __restrict__ bv,
    float* __restrict__ Kout, float* __restrict__ Vout) {
  const int b = blockIdx.z;
  const int o0 = blockIdx.x * 64;
  const float* w = blockIdx.y ? wv : wk;
  const float* bb = blockIdx.y ? bv : bk;
  float* out = blockIdx.y ? Vout : Kout;

  __shared__ float wl[64 * 129];
  __shared__ float ll[32 * 129];
  const int tid = threadIdx.x;
  const int o = tid & 63, ng = tid >> 6;  // each thread: 1 o x 8 n
  float acc[8];
#pragma unroll
  for (int j = 0; j < 8; ++j) acc[j] = 0.f;

  for (int kc = 0; kc < LIN; kc += 128) {
    for (int e = tid; e < 64 * 128; e += 256)
      wl[(e >> 7) * 129 + (e & 127)] =
          w[(size_t)(o0 + (e >> 7)) * LIN + kc + (e & 127)];
    for (int e = tid; e < 32 * 128; e += 256)
      ll[(e >> 7) * 129 + (e & 127)] =
          l[(size_t)b * NL * LIN + (size_t)(e >> 7) * LIN + kc + (e & 127)];
    __syncthreads();
    for (int k = 0; k < 128; ++k) {
      const float wv_ = wl[o * 129 + k];
#pragma unroll
      for (int j = 0; j < 8; ++j) acc[j] += wv_ * ll[(ng * 8 + j) * 129 + k];
    }
    __syncthreads();
  }
  const float bval = bb[o0 + o];
#pragma unroll
  for (int j = 0; j < 8; ++j) {
    const int n = ng * 8 + j;
    out[((size_t)b * DIM + o0 + o) * NL + n] =
        (acc[j] + bval) * lmask[b * NL + n];
  }
}

// ---------------------------------------------------------------- attention
// Per (b,h,m): scores over 32 keys (dk=128), softmax, weighted sum of v (dv=128).
__global__ __launch_bounds__(256) void attn_kernel(
    const f16* __restrict__ Q, const float* __restrict__ qmean,
    const float* __restrict__ qrinv, const float* __restrict__ Kk,
    const float* __restrict__ Vv, const float* __restrict__ lmask,
    float* __restrict__ Out) {
  const int b = blockIdx.z, h = blockIdx.y;
  __shared__ float ks[128 * NL], vs[128 * NL], qm[128], qr[128], bs[NL];
  const int tid = threadIdx.x;
  const float* kbase = Kk + ((size_t)b * DIM + h * 128) * NL;
  const float* vbase = Vv + ((size_t)b * DIM + h * 128) * NL;
  for (int i = tid; i < 128 * NL; i += 256) {
    ks[i] = kbase[i];
    vs[i] = vbase[i];
  }
  if (tid < 128) {
    qm[tid] = qmean[b * DIM + h * 128 + tid];
    qr[tid] = qrinv[b * DIM + h * 128 + tid];
  }
  if (tid < NL) bs[tid] = (lmask[b * NL + tid] - 1.0f) * 10000.0f;
  __syncthreads();

  const int mloc = blockIdx.x * 256 + tid;
  if (mloc >= HW) return;
  const size_t m = (size_t)b * HW + mloc;
  const f16* qrow = Q + m * DIM + h * 128;

  float sc[32];
#pragma unroll
  for (int n = 0; n < 32; ++n) sc[n] = 0.f;

  for (int d8 = 0; d8 < 16; ++d8) {
    const f16x8 qv = *(const f16x8*)(qrow + d8 * 8);
#pragma unroll
    for (int j = 0; j < 8; ++j) {
      const int d = d8 * 8 + j;
      const float qd = ((float)qv[j] - qm[d]) * qr[d];
      const float4* kr = (const float4*)&ks[d * 32];
#pragma unroll
      for (int n4 = 0; n4 < 8; ++n4) {
        const float4 kk = kr[n4];
        sc[n4 * 4 + 0] += qd * kk.x;
        sc[n4 * 4 + 1] += qd * kk.y;
        sc[n4 * 4 + 2] += qd * kk.z;
        sc[n4 * 4 + 3] += qd * kk.w;
      }
    }
  }
  float mx = -1e30f;
#pragma unroll
  for (int n = 0; n < 32; ++n) {
    sc[n] = sc[n] * 0.03125f + bs[n];  // * KC^-0.5 then masked bias
    mx = fmaxf(mx, sc[n]);
  }
  float sum = 0.f;
#pragma unroll
  for (int n = 0; n < 32; ++n) {
    sc[n] = __expf(sc[n] - mx);
    sum += sc[n];
  }
  const float rs = 1.0f / sum;

  float* orow = Out + m * DIM + h * 128;
  for (int dv8 = 0; dv8 < 16; ++dv8) {
    float ov[8];
#pragma unroll
    for (int j = 0; j < 8; ++j) {
      const float4* vr = (const float4*)&vs[(dv8 * 8 + j) * 32];
      float a = 0.f;
#pragma unroll
      for (int n4 = 0; n4 < 8; ++n4) {
        const float4 vv = vr[n4];
        a += sc[n4 * 4 + 0] * vv.x + sc[n4 * 4 + 1] * vv.y +
             sc[n4 * 4 + 2] * vv.z + sc[n4 * 4 + 3] * vv.w;
      }
      ov[j] = a * rs;
    }
    float4* op = (float4*)(orow + dv8 * 8);
    op[0] = make_float4(ov[0], ov[1], ov[2], ov[3]);
    op[1] = make_float4(ov[4], ov[5], ov[6], ov[7]);
  }
}

// ---------------------------------------------------------------- center (attn - colmean) -> f16
__global__ void center_kernel(const float* __restrict__ X,
                              const float* __restrict__ mean,
                              f16* __restrict__ out, int nchunks) {
  const int i = blockIdx.x * 256 + threadIdx.x;
  if (i >= nchunks) return;
  const size_t e = (size_t)i * 8;
  const int mrow = (int)(e >> 10);
  const int o = (int)(e & 1023);
  const int b = mrow / HW;
  const float4* p = (const float4*)(X + e);
  const float4 a = p[0], c = p[1];
  const float* mn = mean + b * DIM + o;
  f16x8 r = {(f16)(a.x - mn[0]), (f16)(a.y - mn[1]), (f16)(a.z - mn[2]),
             (f16)(a.w - mn[3]), (f16)(c.x - mn[4]), (f16)(c.y - mn[5]),
             (f16)(c.z - mn[6]), (f16)(c.w - mn[7])};
  *((f16x8*)out + i) = r;
}

// ---------------------------------------------------------------- fuse: mm = vis * inorm(lang_pre)
__global__ void fuse_kernel(const f16* __restrict__ vis,
                            const float* __restrict__ lang,
                            const float* __restrict__ mean,
                            const float* __restrict__ rinv,
                            f16* __restrict__ out, int nchunks) {
  const int i = blockIdx.x * 256 + threadIdx.x;
  if (i >= nchunks) return;
  const size_t e = (size_t)i * 8;
  const int mrow = (int)(e >> 10);
  const int o = (int)(e & 1023);
  const int b = mrow / HW;
  const f16x8 v = *((const f16x8*)vis + i);
  const float4* p = (const float4*)(lang + e);
  const float4 a = p[0], c = p[1];
  const float lv[8] = {a.x, a.y, a.z, a.w, c.x, c.y, c.z, c.w};
  const float* mn = mean + b * DIM + o;
  const float* ri = rinv + b * DIM + o;
  f16x8 r;
#pragma unroll
  for (int j = 0; j < 8; ++j)
    r[j] = (f16)((float)v[j] * ((lv[j] - mn[j]) * ri[j]));
  *((f16x8*)out + i) = r;
}

// ---------------------------------------------------------------- launch
extern "C" void kernel_launch(void* const* d_in, const int* in_sizes, int n_in,
                              void* d_out, int out_size, void* d_ws,
                              size_t ws_size, hipStream_t stream) {
  const float* x     = (const float*)d_in[0];
  const float* l     = (const float*)d_in[1];
  const float* lmask = (const float*)d_in[2];
  const float* vis_w = (const float*)d_in[3];
  const float* vis_b = (const float*)d_in[4];
  const float* fq_w  = (const float*)d_in[5];
  const float* fq_b  = (const float*)d_in[6];
  const float* fk_w  = (const float*)d_in[7];
  const float* fk_b  = (const float*)d_in[8];
  const float* fv_w  = (const float*)d_in[9];
  const float* fv_b  = (const float*)d_in[10];
  const float* W_w   = (const float*)d_in[11];
  const float* W_b   = (const float*)d_in[12];
  const float* pm_w  = (const float*)d_in[13];
  const float* pm_b  = (const float*)d_in[14];

  char* ws = (char*)d_ws;
  const size_t SB = (size_t)MTOT * DIM * 2;  // one f16 [M,1024] buffer
  f16* Ah = (f16*)(ws);                      // x_f16 -> centered attn -> mm
  f16* Bh = (f16*)(ws + SB);                 // vis
  f16* Ch = (f16*)(ws + 2 * SB);             // q (f16)
  float* Df = (float*)(ws + 3 * SB);         // attn f32 -> lang_pre f32 (2*SB bytes)
  char* wsp = ws + 5 * SB;
  f16* vis_wh = (f16*)(wsp);
  f16* fq_wh  = (f16*)(wsp + (1 << 21));
  f16* W_wh   = (f16*)(wsp + 2 * (1 << 21));
  f16* pm_wh  = (f16*)(wsp + 3 * (1 << 21));
  float* Kout = (float*)(wsp + 4 * (1 << 21));
  float* Vout = (float*)(wsp + 4 * (1 << 21) + (1 << 20));
  float* st   = (float*)(wsp + 4 * (1 << 21) + 2 * (1 << 20));
  float* qmean = st;
  float* qrinv = st + 8192;
  float* amean = st + 16384;
  float* arinv = st + 24576;
  float* lmean = st + 32768;
  float* lrinv = st + 40960;
  float* psum  = (float*)(wsp + 4 * (1 << 21) + 3 * (1 << 20));  // CSPLIT*NB*DIM
  float* psq   = psum + (size_t)CSPLIT * NB * DIM;

  const int NCH_BIG = MTOT * DIM / 8;  // 5,607,424 chunks of 8
  const int NCH_W = DIM * DIM / 8;     // 131,072

  cvt_f32_f16<<<(NCH_BIG + 255) / 256, 256, 0, stream>>>(x, Ah, NCH_BIG);
  cvt_f32_f16<<<(NCH_W + 255) / 256, 256, 0, stream>>>(vis_w, vis_wh, NCH_W);
  cvt_f32_f16<<<(NCH_W + 255) / 256, 256, 0, stream>>>(fq_w, fq_wh, NCH_W);
  cvt_f32_f16<<<(NCH_W + 255) / 256, 256, 0, stream>>>(W_w, W_wh, NCH_W);
  cvt_f32_f16<<<(NCH_W + 255) / 256, 256, 0, stream>>>(pm_w, pm_wh, NCH_W);

  kv_gemm<<<dim3(16, 2, 8), 256, 0, stream>>>(l, lmask, fk_w, fk_b, fv_w, fv_b,
                                              Kout, Vout);

  const dim3 ggrid(8, MTILES);
  gemm_nt<0><<<ggrid, 256, 0, stream>>>(Ah, vis_wh, vis_b, Bh, MTOT);  // vis
  gemm_nt<1><<<ggrid, 256, 0, stream>>>(Ah, fq_wh, fq_b, Ch, MTOT);    // q_pre

  colstats_partial<f16><<<dim3(CSPLIT, NB), 256, 0, stream>>>(Ch, psum, psq);
  colstats_final<<<32, 256, 0, stream>>>(psum, psq, qmean, qrinv);

  attn_kernel<<<dim3((HW + 255) / 256, 8, 8), 256, 0, stream>>>(
      Ch, qmean, qrinv, Kout, Vout, lmask, Df);

  colstats_partial<float><<<dim3(CSPLIT, NB), 256, 0, stream>>>(Df, psum, psq);
  colstats_final<<<32, 256, 0, stream>>>(psum, psq, amean, arinv);
  center_kernel<<<(NCH_BIG + 255) / 256, 256, 0, stream>>>(Df, amean, Ah,
                                                           NCH_BIG);

  gemm_nt<2><<<ggrid, 256, 0, stream>>>(Ah, W_wh, W_b, Df, MTOT);  // lang_pre f32
  colstats_partial<float><<<dim3(CSPLIT, NB), 256, 0, stream>>>(Df, psum, psq);
  colstats_final<<<32, 256, 0, stream>>>(psum, psq, lmean, lrinv);
  fuse_kernel<<<(NCH_BIG + 255) / 256, 256, 0, stream>>>(Bh, Df, lmean, lrinv,
                                                         Ah, NCH_BIG);

  gemm_nt<3><<<ggrid, 256, 0, stream>>>(Ah, pm_wh, pm_b, d_out, MTOT);  // output
}